// Round 2
// baseline (1050.848 us; speedup 1.0000x reference)
//
#include <hip/hip_runtime.h>

#define NTOK  49
#define CDIM  192
#define NHEAD 6
#define NWIN  1024
#define SCALE 0.17677669529663687f

// LDS layout (bytes):
//  xb  @0      : [64][200] ushort = 25600   (x bf16; row stride 400 B)
//  mskT@0      : [49][65]  float  = 12740   (aliases xb after qkv done)
//  kb  @25600  : [4 tt][6 h][64 lane][16 B] = 24576
//  vt  @50176  : [192 ch][144 B]            = 27648
//  eps @0      : [64][200] float  = 51200   (aliases xb+kb+1KB of vt, all dead)
#define LDS_XB 0
#define LDS_KB 25600
#define LDS_VT 50176
#define SMEM_BYTES 77824

typedef __bf16 bfx8 __attribute__((ext_vector_type(8)));
typedef float  f32x4 __attribute__((ext_vector_type(4)));
typedef unsigned long long ull;

union BF8 { bfx8 v; unsigned short u[8]; ull q[2]; };

__device__ __forceinline__ unsigned short f2bf(float f) {
    unsigned int u = __builtin_bit_cast(unsigned int, f);
    u += 0x7fffu + ((u >> 16) & 1u);
    return (unsigned short)(u >> 16);
}

extern "C" __global__ void wattn_prep(const float* __restrict__ qkv_w,
                                      const float* __restrict__ proj_w,
                                      const float* __restrict__ rpb,
                                      const int*   __restrict__ rel,
                                      const float* __restrict__ qkv_b,
                                      unsigned short* __restrict__ W1s,
                                      unsigned short* __restrict__ W2b,
                                      float* __restrict__ qkvbs,
                                      float* __restrict__ biasT)
{
    const int i = blockIdx.x * 256 + threadIdx.x;
    if (i < 576 * 192) {
        float v = qkv_w[i];
        if (i < 192 * 192) v *= SCALE;          // fold scale into Q rows
        W1s[i] = f2bf(v);
    }
    if (i < 192 * 192) W2b[i] = f2bf(proj_w[i]);
    if (i < 576) qkvbs[i] = (i < 192) ? qkv_b[i] * SCALE : qkv_b[i];
    if (i < NHEAD * NTOK * 64) {                // biasT[h][j][i] (i padded to 64)
        const int h  = i / (NTOK * 64);
        const int j  = (i / 64) % NTOK;
        const int ii = i % 64;
        biasT[i] = (ii < NTOK) ? rpb[rel[ii * NTOK + j] * NHEAD + h] : 0.f;
    }
}

extern "C" __global__ void __launch_bounds__(512, 4)
wattn_fused(const float* __restrict__ x,
            const float* __restrict__ mask,
            const float* __restrict__ proj_b,
            const unsigned short* __restrict__ W1s,
            const unsigned short* __restrict__ W2b,
            const float* __restrict__ qkvbs,
            const float* __restrict__ biasT,
            float* __restrict__ out)
{
    extern __shared__ char smem[];
    unsigned short* xb   = (unsigned short*)(smem + LDS_XB);
    float*          mskT = (float*)(smem + LDS_XB);
    char*           kb   = smem + LDS_KB;
    char*           vt   = smem + LDS_VT;
    float*          eps  = (float*)smem;

    const int b    = blockIdx.x;
    const int tid  = threadIdx.x;
    const int wave = tid >> 6;
    const int lane = tid & 63;
    const int g    = lane >> 4;
    const int jn   = lane & 15;
    const int qt   = wave & 3;   // token tile this wave owns for Q/attention
    const int hh   = wave >> 2;  // head-half: 0 -> heads 0-2, 1 -> heads 3-5

    // ---- stage x -> xb (bf16), zero pad rows 49..63 ----
    {
        unsigned int* z = (unsigned int*)(xb + 49 * 200);
        for (int i = tid; i < 15 * 100; i += 512) z[i] = 0u;
        const float4* xw = (const float4*)(x + (size_t)b * NTOK * CDIM);
        for (int i = tid; i < NTOK * CDIM / 4; i += 512) {
            float4 v = xw[i];
            ull p = (ull)f2bf(v.x) | ((ull)f2bf(v.y) << 16) |
                    ((ull)f2bf(v.z) << 32) | ((ull)f2bf(v.w) << 48);
            *(ull*)(xb + (i / 48) * 200 + (i % 48) * 4) = p;
        }
    }
    __syncthreads();

    // ---- qkv GEMM (transposed outputs via swapped MFMA operands) ----
    // Q: this wave's 6 channel-tiles (its heads) x its token tile -> registers
    BF8 qf[3];
    for (int q = 0; q < 6; ++q) {
        const int oct = hh * 6 + q;
        f32x4 acc = *(const f32x4*)(qkvbs + oct * 16 + 4 * g);
        for (int kk = 0; kk < 6; ++kk) {
            bfx8 a  = *(const bfx8*)(W1s + (size_t)(oct * 16 + jn) * 192 + kk * 32 + g * 8);
            bfx8 xf = *(const bfx8*)(xb + (qt * 16 + jn) * 200 + kk * 32 + g * 8);
            acc = __builtin_amdgcn_mfma_f32_16x16x32_bf16(a, xf, acc, 0, 0, 0);
        }
        for (int r = 0; r < 4; ++r) qf[q >> 1].u[(q & 1) * 4 + r] = f2bf(acc[r]);
    }
    // K (waves 0-3) / V (waves 4-7): 3 channel-tiles x 4 token tiles -> LDS
    for (int oo = 0; oo < 3; ++oo) {
        const int oct = (hh ? 24 : 12) + qt * 3 + oo;
        bfx8 af[6];
        for (int kk = 0; kk < 6; ++kk)
            af[kk] = *(const bfx8*)(W1s + (size_t)(oct * 16 + jn) * 192 + kk * 32 + g * 8);
        const f32x4 bias4 = *(const f32x4*)(qkvbs + oct * 16 + 4 * g);
        for (int tt = 0; tt < 4; ++tt) {
            f32x4 acc = bias4;
            for (int kk = 0; kk < 6; ++kk) {
                bfx8 xf = *(const bfx8*)(xb + (tt * 16 + jn) * 200 + kk * 32 + g * 8);
                acc = __builtin_amdgcn_mfma_f32_16x16x32_bf16(af[kk], xf, acc, 0, 0, 0);
            }
            if (!hh) {
                const int qct = oct - 12;                  // 0..11; head = qct>>1
                ull p = (ull)f2bf(acc[0]) | ((ull)f2bf(acc[1]) << 16) |
                        ((ull)f2bf(acc[2]) << 32) | ((ull)f2bf(acc[3]) << 48);
                *(ull*)(kb + ((tt * 6 + (qct >> 1)) * 64 + lane) * 16 + (qct & 1) * 8) = p;
            } else {
                const int chb = (oct - 24) * 16;
                const int off = (tt >> 1) * 64 + (jn >> 2) * 16 + (tt & 1) * 8 + (jn & 3) * 2;
                for (int r = 0; r < 4; ++r)
                    *(unsigned short*)(vt + (chb + 4 * g + r) * 144 + off) = f2bf(acc[r]);
            }
        }
    }
    __syncthreads();

    // ---- stage transposed mask into (now dead) xb region ----
    {
        const float* mw = mask + (size_t)(b & (NWIN - 1)) * (NTOK * NTOK);
        for (int i = tid; i < NTOK * NTOK; i += 512)
            mskT[(i % NTOK) * 65 + (i / NTOK)] = mw[i];   // mskT[j][i]
    }
    __syncthreads();

    // ---- attention (barrier-free): 3 heads per wave ----
    f32x4 oacc[3][2];
    float inv[3];
    for (int hl = 0; hl < 3; ++hl)
        for (int ct = 0; ct < 2; ++ct) oacc[hl][ct] = (f32x4){0.f, 0.f, 0.f, 0.f};

    for (int hl = 0; hl < 3; ++hl) {
        const int H = hh * 3 + hl;
        // bias + mask (transposed reads: i = q-row = lane&15 -> coalesced)
        float bm[4][4];
        for (int kt = 0; kt < 4; ++kt)
            for (int r = 0; r < 4; ++r) {
                int j = kt * 16 + 4 * g + r;
                int jc = j < NTOK ? j : NTOK - 1;
                bm[kt][r] = biasT[(H * NTOK + jc) * 64 + qt * 16 + jn] +
                            mskT[jc * 65 + qt * 16 + jn];
            }
        // S^T = K · Q^T  (4 MFMAs, all operands register/1-read)
        f32x4 s[4];
        for (int kt = 0; kt < 4; ++kt) {
            bfx8 kf = *(const bfx8*)(kb + ((kt * 6 + H) * 64 + lane) * 16);
            f32x4 z = {0.f, 0.f, 0.f, 0.f};
            s[kt] = __builtin_amdgcn_mfma_f32_16x16x32_bf16(kf, qf[hl].v, z, 0, 0, 0);
        }
        // logits + wave-parallel softmax (row = jn, spread over 4 g-groups)
        float p[4][4], mx = -1e30f;
        for (int kt = 0; kt < 4; ++kt)
            for (int r = 0; r < 4; ++r) {
                int j = kt * 16 + 4 * g + r;
                float v = (j < NTOK) ? s[kt][r] + bm[kt][r] : -1e30f;
                p[kt][r] = v;
                mx = fmaxf(mx, v);
            }
        mx = fmaxf(mx, __shfl_xor(mx, 16));
        mx = fmaxf(mx, __shfl_xor(mx, 32));
        float sum = 0.f;
        for (int kt = 0; kt < 4; ++kt)
            for (int r = 0; r < 4; ++r) {
                p[kt][r] = __expf(p[kt][r] - mx);
                sum += p[kt][r];
            }
        sum += __shfl_xor(sum, 16);
        sum += __shfl_xor(sum, 32);
        inv[hl] = 1.f / sum;
        // pack P (unnormalized) into two K32 B-frags
        BF8 p01, p23;
        for (int r = 0; r < 4; ++r) {
            p01.u[r] = f2bf(p[0][r]); p01.u[4 + r] = f2bf(p[1][r]);
            p23.u[r] = f2bf(p[2][r]); p23.u[4 + r] = f2bf(p[3][r]);
        }
        // O^T += V^T · P  (4 MFMAs; V frags one b128 each)
        for (int ct = 0; ct < 2; ++ct) {
            const int row = H * 32 + ct * 16 + jn;
            bfx8 v0 = *(const bfx8*)(vt + row * 144 + g * 16);
            bfx8 v1 = *(const bfx8*)(vt + row * 144 + 64 + g * 16);
            oacc[hl][ct] = __builtin_amdgcn_mfma_f32_16x16x32_bf16(v0, p01.v, oacc[hl][ct], 0, 0, 0);
            oacc[hl][ct] = __builtin_amdgcn_mfma_f32_16x16x32_bf16(v1, p23.v, oacc[hl][ct], 0, 0, 0);
        }
    }

    // ---- proj GEMM (partial over this wave's 96 channels), all in-register ----
    BF8 obf[3];
    for (int hl = 0; hl < 3; ++hl)
        for (int r = 0; r < 4; ++r) {
            obf[hl].u[r]     = f2bf(oacc[hl][0][r] * inv[hl]);
            obf[hl].u[4 + r] = f2bf(oacc[hl][1][r] * inv[hl]);
        }
    f32x4 outacc[12];
    for (int c2t = 0; c2t < 12; ++c2t) {
        f32x4 acc = {0.f, 0.f, 0.f, 0.f};
        for (int hl = 0; hl < 3; ++hl) {
            const int H = hh * 3 + hl;
            BF8 wf;
            wf.q[0] = *(const ull*)(W2b + (size_t)(c2t * 16 + jn) * 192 + H * 32 + 4 * g);
            wf.q[1] = *(const ull*)(W2b + (size_t)(c2t * 16 + jn) * 192 + H * 32 + 16 + 4 * g);
            acc = __builtin_amdgcn_mfma_f32_16x16x32_bf16(wf.v, obf[hl].v, acc, 0, 0, 0);
        }
        outacc[c2t] = acc;
    }
    __syncthreads();   // kb/vt/mskT dead -> eps region free

    // ---- cross-half reduction + bias, then coalesced store ----
    if (hh == 1) {
        for (int c2t = 0; c2t < 12; ++c2t)
            for (int r = 0; r < 4; ++r)
                eps[(qt * 16 + jn) * 200 + c2t * 16 + 4 * g + r] = outacc[c2t][r];
    }
    __syncthreads();
    if (hh == 0) {
        for (int c2t = 0; c2t < 12; ++c2t) {
            f32x4 pb = *(const f32x4*)(proj_b + c2t * 16 + 4 * g);
            for (int r = 0; r < 4; ++r) {
                const int idx = (qt * 16 + jn) * 200 + c2t * 16 + 4 * g + r;
                eps[idx] += outacc[c2t][r] + pb[r];
            }
        }
    }
    __syncthreads();
    float* outp = out + (size_t)b * NTOK * CDIM;
    for (int i = tid; i < NTOK * 48; i += 512) {
        const int row = i / 48, seg = i % 48;
        f32x4 v = *(const f32x4*)(eps + row * 200 + seg * 4);
        *(f32x4*)(outp + row * 192 + seg * 4) = v;
    }
}

extern "C" void kernel_launch(void* const* d_in, const int* in_sizes, int n_in,
                              void* d_out, int out_size, void* d_ws, size_t ws_size,
                              hipStream_t stream) {
    const float* x      = (const float*)d_in[0];
    const float* mask   = (const float*)d_in[1];
    const float* qkv_w  = (const float*)d_in[2];
    const float* qkv_b  = (const float*)d_in[3];
    const float* proj_w = (const float*)d_in[4];
    const float* proj_b = (const float*)d_in[5];
    const float* rpb    = (const float*)d_in[6];
    const int*   rel    = (const int*)d_in[7];
    float* outp = (float*)d_out;

    char* ws = (char*)d_ws;
    unsigned short* W1s = (unsigned short*)ws;                     // 221184 B
    unsigned short* W2b = (unsigned short*)(ws + 221184);          //  73728 B
    float* qkvbs        = (float*)(ws + 221184 + 73728);           //   2304 B
    float* biasT        = (float*)(ws + 221184 + 73728 + 2304);    //  75264 B

    hipFuncSetAttribute((const void*)wattn_fused,
                        hipFuncAttributeMaxDynamicSharedMemorySize, SMEM_BYTES);

    wattn_prep<<<432, 256, 0, stream>>>(qkv_w, proj_w, rpb, rel, qkv_b,
                                        W1s, W2b, qkvbs, biasT);
    wattn_fused<<<8192, 512, SMEM_BYTES, stream>>>(x, mask, proj_b,
                                                   W1s, W2b, qkvbs, biasT, outp);
}

// Round 3
// 748.171 us; speedup vs baseline: 1.4046x; 1.4046x over previous
//
#include <hip/hip_runtime.h>

#define NTOK  49
#define NWIN  1024
#define SCALE 0.17677669529663687f

// LDS layout (bytes), per block (2 windows):
//  xb[w]   @ w*25600          : [64][200] ushort (x bf16)      -- dead after qkv
//  mskT[w] @ w*25600          : [49][65] f32 (aliases xb)      -- attn phase
//  obx     @ 0                : [w][hh][qt][hl][64][16B]=49152 -- proj phase (aliases xb/mskT)
//  kb[w]   @ 51200 + w*24576  : [4 tt][6 h][64 lane][16 B]
//  vt[w]   @ 100352 + w*27648 : [192 ch][144 B]
#define SMEM_BYTES 155648

typedef __bf16 bfx8 __attribute__((ext_vector_type(8)));
typedef float  f32x4 __attribute__((ext_vector_type(4)));
typedef unsigned long long ull;

union BF8 { bfx8 v; unsigned short u[8]; ull q[2]; };

__device__ __forceinline__ unsigned short f2bf(float f) {
    unsigned int u = __builtin_bit_cast(unsigned int, f);
    u += 0x7fffu + ((u >> 16) & 1u);
    return (unsigned short)(u >> 16);
}
__device__ __forceinline__ ull pack4(f32x4 a) {
    return (ull)f2bf(a[0]) | ((ull)f2bf(a[1]) << 16) |
           ((ull)f2bf(a[2]) << 32) | ((ull)f2bf(a[3]) << 48);
}

// Pre-swizzle weights into wave-contiguous MFMA fragment order.
// W1f[oct 0..35][kk 0..5][lane][8]: lane(g,jn) holds qkv_w[oct*16+jn][kk*32+g*8 ..+8]
// W2p[c2t*6+H][lane][8]: e<4 -> proj_w[c2t*16+jn][H*32+4g+e]; e>=4 -> [.. +16+4g+(e-4)]
extern "C" __global__ void wattn_prep(const float* __restrict__ qkv_w,
                                      const float* __restrict__ proj_w,
                                      const float* __restrict__ rpb,
                                      const int*   __restrict__ rel,
                                      const float* __restrict__ qkv_b,
                                      unsigned short* __restrict__ W1f,
                                      unsigned short* __restrict__ W2p,
                                      float* __restrict__ qkvbs,
                                      float* __restrict__ biasT)
{
    const int i = blockIdx.x * 256 + threadIdx.x;
    if (i < 110592) {
        const int e = i & 7, l = (i >> 3) & 63, f = i >> 9;
        const int kk = f % 6, oct = f / 6;
        const int R = oct * 16 + (l & 15), C = kk * 32 + (l >> 4) * 8 + e;
        float v = qkv_w[R * 192 + C];
        if (oct < 12) v *= SCALE;
        W1f[i] = f2bf(v);
    }
    if (i < 36864) {
        const int e = i & 7, l = (i >> 3) & 63, f = i >> 9;
        const int c2t = f / 6, H = f % 6;
        const int R = c2t * 16 + (l & 15);
        const int C = H * 32 + (e >> 2) * 16 + (l >> 4) * 4 + (e & 3);
        W2p[i] = f2bf(proj_w[R * 192 + C]);
    }
    if (i < 576) qkvbs[i] = (i < 192) ? qkv_b[i] * SCALE : qkv_b[i];
    if (i < 6 * NTOK * 64) {                 // biasT[h][j][i], i padded to 64
        const int h = i / (NTOK * 64), j = (i / 64) % NTOK, ii = i % 64;
        biasT[i] = (ii < NTOK) ? rpb[rel[ii * NTOK + j] * 6 + h] : 0.f;
    }
}

extern "C" __global__ void __launch_bounds__(512, 2)
wattn_fused(const float* __restrict__ x,
            const float* __restrict__ mask,
            const float* __restrict__ proj_b,
            const unsigned short* __restrict__ W1f,
            const unsigned short* __restrict__ W2p,
            const float* __restrict__ qkvbs,
            const float* __restrict__ biasT,
            float* __restrict__ out)
{
    extern __shared__ char smem[];
    char* const OBX = smem;
    #define XB(w) (smem + (w) * 25600)
    #define KB(w) (smem + 51200 + (w) * 24576)
    #define VT(w) (smem + 100352 + (w) * 27648)

    const int tid  = threadIdx.x;
    const int wave = tid >> 6;
    const int lane = tid & 63;
    const int g    = lane >> 4;
    const int jn   = lane & 15;
    const int qt   = wave & 3;
    const int hh   = wave >> 2;
    const size_t b2 = (size_t)blockIdx.x * 2;

    // ---- prefetch mask (2 windows) into registers; stage x -> bf16 LDS ----
    float mreg[10];
    {
        const float* mb = mask + (b2 & (NWIN - 1)) * (NTOK * NTOK);
#pragma unroll
        for (int u = 0; u < 10; ++u) {
            const int i = tid + u * 512;
            mreg[u] = (i < 2 * NTOK * NTOK) ? mb[i] : 0.f;
        }
    }
#pragma unroll
    for (int u = 0; u < 6; ++u) {            // zero pad rows 49..63, both windows
        const int i = tid + u * 512;
        if (i < 3000) {
            const int w = i / 1500, e = i % 1500;
            *(unsigned int*)(XB(w) + (49 + e / 100) * 400 + (e % 100) * 4) = 0u;
        }
    }
    {
        const float4* xw = (const float4*)(x + b2 * 9408);
#pragma unroll
        for (int u = 0; u < 10; ++u) {
            const int i = tid + u * 512;
            if (i < 4704) {
                float4 v = xw[i];
                const int w = i / 2352, e = i % 2352;
                *(ull*)(XB(w) + (e / 48) * 400 + (e % 48) * 8) =
                    (ull)f2bf(v.x) | ((ull)f2bf(v.y) << 16) |
                    ((ull)f2bf(v.z) << 32) | ((ull)f2bf(v.w) << 48);
            }
        }
    }
    __syncthreads();                                              // B1

    // ---- Q: this wave's 6 channel-tiles x its token tile, both windows ----
    bfx8 xq[2][6];
#pragma unroll
    for (int w = 0; w < 2; ++w)
#pragma unroll
        for (int kk = 0; kk < 6; ++kk)
            xq[w][kk] = *(const bfx8*)(XB(w) + (qt * 16 + jn) * 400 + kk * 64 + g * 16);

    BF8 qf[2][3];
#pragma unroll
    for (int q = 0; q < 6; ++q) {
        const int oct = hh * 6 + q;
        bfx8 wq[6];
#pragma unroll
        for (int kk = 0; kk < 6; ++kk)
            wq[kk] = *(const bfx8*)(W1f + ((size_t)(oct * 6 + kk) * 64 + lane) * 8);
        const f32x4 binit = *(const f32x4*)(qkvbs + oct * 16 + 4 * g);
#pragma unroll
        for (int w = 0; w < 2; ++w) {
            f32x4 acc = binit;
#pragma unroll
            for (int kk = 0; kk < 6; ++kk)
                acc = __builtin_amdgcn_mfma_f32_16x16x32_bf16(wq[kk], xq[w][kk], acc, 0, 0, 0);
#pragma unroll
            for (int r = 0; r < 4; ++r)
                qf[w][q >> 1].u[(q & 1) * 4 + r] = f2bf(acc[r]);
        }
    }

    // ---- K (hh=0, swapped) / V (hh=1, unswapped): 3 ch-tiles x 4 tok-tiles x 2 w ----
    bfx8 af[3][6];
#pragma unroll
    for (int oo = 0; oo < 3; ++oo) {
        const int oct = (hh ? 24 : 12) + qt * 3 + oo;
#pragma unroll
        for (int kk = 0; kk < 6; ++kk)
            af[oo][kk] = *(const bfx8*)(W1f + ((size_t)(oct * 6 + kk) * 64 + lane) * 8);
    }
#pragma unroll
    for (int tt = 0; tt < 4; ++tt) {
        bfx8 xf[2][6];
#pragma unroll
        for (int w = 0; w < 2; ++w)
#pragma unroll
            for (int kk = 0; kk < 6; ++kk)
                xf[w][kk] = *(const bfx8*)(XB(w) + (tt * 16 + jn) * 400 + kk * 64 + g * 16);
#pragma unroll
        for (int oo = 0; oo < 3; ++oo) {
            const int ct12 = qt * 3 + oo;                         // 0..11
            if (!hh) {
                const f32x4 binit = *(const f32x4*)(qkvbs + (12 + ct12) * 16 + 4 * g);
#pragma unroll
                for (int w = 0; w < 2; ++w) {
                    f32x4 acc = binit;
#pragma unroll
                    for (int kk = 0; kk < 6; ++kk)
                        acc = __builtin_amdgcn_mfma_f32_16x16x32_bf16(af[oo][kk], xf[w][kk], acc, 0, 0, 0);
                    *(ull*)(KB(w) + ((tt * 6 + (ct12 >> 1)) * 64 + lane) * 16 + (ct12 & 1) * 8) = pack4(acc);
                }
            } else {
                const float bv = qkvbs[(24 + ct12) * 16 + jn];
                const f32x4 binit = {bv, bv, bv, bv};
#pragma unroll
                for (int w = 0; w < 2; ++w) {
                    f32x4 acc = binit;
#pragma unroll
                    for (int kk = 0; kk < 6; ++kk)
                        acc = __builtin_amdgcn_mfma_f32_16x16x32_bf16(xf[w][kk], af[oo][kk], acc, 0, 0, 0);
                    *(ull*)(VT(w) + (ct12 * 16 + jn) * 144 + (tt >> 1) * 64 + g * 16 + (tt & 1) * 8) = pack4(acc);
                }
            }
        }
    }
    __syncthreads();                                              // B2

    // ---- stage transposed mask into dead xb region ----
#pragma unroll
    for (int u = 0; u < 10; ++u) {
        const int i = tid + u * 512;
        if (i < 2 * NTOK * NTOK) {
            const int w = i / (NTOK * NTOK), e = i % (NTOK * NTOK);
            *(float*)(XB(w) + ((e % NTOK) * 65 + e / NTOK) * 4) = mreg[u];
        }
    }
    __syncthreads();                                              // B3

    // ---- attention: 3 heads x 2 windows per wave, barrier-free ----
    float mv[2][4][4];
#pragma unroll
    for (int w = 0; w < 2; ++w)
#pragma unroll
        for (int kt = 0; kt < 4; ++kt)
#pragma unroll
            for (int r = 0; r < 4; ++r) {
                const int j = kt * 16 + 4 * g + r;
                const int jc = j < NTOK ? j : NTOK - 1;
                mv[w][kt][r] = *(const float*)(XB(w) + (jc * 65 + qt * 16 + jn) * 4);
            }

    BF8 obf[2][3];
#pragma unroll
    for (int hl = 0; hl < 3; ++hl) {
        const int H = hh * 3 + hl;
        float bm[4][4];
#pragma unroll
        for (int kt = 0; kt < 4; ++kt)
#pragma unroll
            for (int r = 0; r < 4; ++r) {
                const int j = kt * 16 + 4 * g + r;
                const int jc = j < NTOK ? j : NTOK - 1;
                bm[kt][r] = biasT[((size_t)H * NTOK + jc) * 64 + qt * 16 + jn];
            }
#pragma unroll
        for (int w = 0; w < 2; ++w) {
            f32x4 s[4];
#pragma unroll
            for (int kt = 0; kt < 4; ++kt) {
                bfx8 kf = *(const bfx8*)(KB(w) + ((kt * 6 + H) * 64 + lane) * 16);
                f32x4 z = {0.f, 0.f, 0.f, 0.f};
                s[kt] = __builtin_amdgcn_mfma_f32_16x16x32_bf16(kf, qf[w][hl].v, z, 0, 0, 0);
            }
            float p[4][4], mx = -1e30f;
#pragma unroll
            for (int kt = 0; kt < 4; ++kt)
#pragma unroll
                for (int r = 0; r < 4; ++r) {
                    const int j = kt * 16 + 4 * g + r;
                    const float v = (j < NTOK) ? s[kt][r] + bm[kt][r] + mv[w][kt][r] : -1e30f;
                    p[kt][r] = v;
                    mx = fmaxf(mx, v);
                }
            mx = fmaxf(mx, __shfl_xor(mx, 16));
            mx = fmaxf(mx, __shfl_xor(mx, 32));
            float sum = 0.f;
#pragma unroll
            for (int kt = 0; kt < 4; ++kt)
#pragma unroll
                for (int r = 0; r < 4; ++r) {
                    p[kt][r] = __expf(p[kt][r] - mx);
                    sum += p[kt][r];
                }
            sum += __shfl_xor(sum, 16);
            sum += __shfl_xor(sum, 32);
            const float inv = 1.f / sum;
            BF8 p01, p23;
#pragma unroll
            for (int r = 0; r < 4; ++r) {
                p01.u[r] = f2bf(p[0][r]); p01.u[4 + r] = f2bf(p[1][r]);
                p23.u[r] = f2bf(p[2][r]); p23.u[4 + r] = f2bf(p[3][r]);
            }
#pragma unroll
            for (int ct = 0; ct < 2; ++ct) {
                const int row = H * 32 + ct * 16 + jn;
                bfx8 v0 = *(const bfx8*)(VT(w) + row * 144 + g * 16);
                bfx8 v1 = *(const bfx8*)(VT(w) + row * 144 + 64 + g * 16);
                f32x4 o = {0.f, 0.f, 0.f, 0.f};
                o = __builtin_amdgcn_mfma_f32_16x16x32_bf16(v0, p01.v, o, 0, 0, 0);
                o = __builtin_amdgcn_mfma_f32_16x16x32_bf16(v1, p23.v, o, 0, 0, 0);
#pragma unroll
                for (int r = 0; r < 4; ++r)
                    obf[w][hl].u[ct * 4 + r] = f2bf(o[r] * inv);
            }
        }
    }
    __syncthreads();                                              // B4

    // ---- exchange O frags across head-halves (bf16, frag-blocked) ----
#pragma unroll
    for (int w = 0; w < 2; ++w)
#pragma unroll
        for (int hl = 0; hl < 3; ++hl)
            *(bfx8*)(OBX + ((((w * 2 + hh) * 4 + qt) * 3 + hl) * 64 + lane) * 16) = obf[w][hl].v;
    __syncthreads();                                              // B5

    // ---- proj: wave handles 6 out-ch tiles (its half), full K=192, direct store ----
    const int oh = 1 - hh;
    float* outp = out + b2 * 9408;
#pragma unroll
    for (int c6 = 0; c6 < 6; ++c6) {
        const int c2t = hh * 6 + c6;
        bfx8 wf[6];
#pragma unroll
        for (int H = 0; H < 6; ++H)
            wf[H] = *(const bfx8*)(W2p + ((size_t)(c2t * 6 + H) * 64 + lane) * 8);
        const f32x4 pb = *(const f32x4*)(proj_b + c2t * 16 + 4 * g);
#pragma unroll
        for (int w = 0; w < 2; ++w) {
            f32x4 acc = pb;
#pragma unroll
            for (int hl = 0; hl < 3; ++hl) {
                acc = __builtin_amdgcn_mfma_f32_16x16x32_bf16(wf[hh * 3 + hl], obf[w][hl].v, acc, 0, 0, 0);
                bfx8 ob2 = *(const bfx8*)(OBX + ((((w * 2 + oh) * 4 + qt) * 3 + hl) * 64 + lane) * 16);
                acc = __builtin_amdgcn_mfma_f32_16x16x32_bf16(wf[oh * 3 + hl], ob2, acc, 0, 0, 0);
            }
            if (qt * 16 + jn < NTOK)
                *(f32x4*)(outp + (size_t)w * 9408 + (qt * 16 + jn) * 192 + c2t * 16 + 4 * g) = acc;
        }
    }
}

extern "C" void kernel_launch(void* const* d_in, const int* in_sizes, int n_in,
                              void* d_out, int out_size, void* d_ws, size_t ws_size,
                              hipStream_t stream) {
    const float* x      = (const float*)d_in[0];
    const float* mask   = (const float*)d_in[1];
    const float* qkv_w  = (const float*)d_in[2];
    const float* qkv_b  = (const float*)d_in[3];
    const float* proj_w = (const float*)d_in[4];
    const float* proj_b = (const float*)d_in[5];
    const float* rpb    = (const float*)d_in[6];
    const int*   rel    = (const int*)d_in[7];
    float* outp = (float*)d_out;

    char* ws = (char*)d_ws;
    unsigned short* W1f = (unsigned short*)ws;                     // 221184 B
    unsigned short* W2p = (unsigned short*)(ws + 221184);          //  73728 B
    float* qkvbs        = (float*)(ws + 221184 + 73728);           //   2304 B
    float* biasT        = (float*)(ws + 221184 + 73728 + 2304);    //  75264 B

    hipFuncSetAttribute((const void*)wattn_fused,
                        hipFuncAttributeMaxDynamicSharedMemorySize, SMEM_BYTES);

    wattn_prep<<<432, 256, 0, stream>>>(qkv_w, proj_w, rpb, rel, qkv_b,
                                        W1f, W2p, qkvbs, biasT);
    wattn_fused<<<4096, 512, SMEM_BYTES, stream>>>(x, mask, proj_b,
                                                   W1f, W2p, qkvbs, biasT, outp);
}

// Round 4
// 747.388 us; speedup vs baseline: 1.4060x; 1.0010x over previous
//
#include <hip/hip_runtime.h>

#define NTOK  49
#define NWIN  1024
#define SCALE 0.17677669529663687f

// LDS layout (bytes), per block (2 windows):
//  xb[w]   @ w*25600          : [64][200] ushort (x bf16)      -- dead after qkv
//  mskT[w] @ w*25600          : [49][65] f32 (aliases xb)      -- attn phase
//  obx     @ 0                : [w][hh][qt][hl][64][16B]=49152 -- proj phase (aliases xb/mskT)
//  kb[w]   @ 51200 + w*24576  : [4 tt][6 h][64 lane][16 B]
//  vt[w]   @ 100352 + w*27648 : [192 ch][144 B]
#define SMEM_BYTES 155648

typedef __bf16 bfx8 __attribute__((ext_vector_type(8)));
typedef float  f32x4 __attribute__((ext_vector_type(4)));
typedef unsigned long long ull;

union BF8 { bfx8 v; unsigned short u[8]; ull q[2]; };

__device__ __forceinline__ unsigned short f2bf(float f) {
    unsigned int u = __builtin_bit_cast(unsigned int, f);
    u += 0x7fffu + ((u >> 16) & 1u);
    return (unsigned short)(u >> 16);
}
__device__ __forceinline__ ull pack4(f32x4 a) {
    return (ull)f2bf(a[0]) | ((ull)f2bf(a[1]) << 16) |
           ((ull)f2bf(a[2]) << 32) | ((ull)f2bf(a[3]) << 48);
}

// Pre-swizzle weights into wave-contiguous MFMA fragment order.
// W1f[oct 0..35][kk 0..5][lane][8]: lane(g,jn) holds qkv_w[oct*16+jn][kk*32+g*8 ..+8]
// W2p[c2t*6+H][lane][8]: e<4 -> proj_w[c2t*16+jn][H*32+4g+e]; e>=4 -> [.. +16+4g+(e-4)]
extern "C" __global__ void wattn_prep(const float* __restrict__ qkv_w,
                                      const float* __restrict__ proj_w,
                                      const float* __restrict__ rpb,
                                      const int*   __restrict__ rel,
                                      const float* __restrict__ qkv_b,
                                      unsigned short* __restrict__ W1f,
                                      unsigned short* __restrict__ W2p,
                                      float* __restrict__ qkvbs,
                                      float* __restrict__ biasT)
{
    const int i = blockIdx.x * 256 + threadIdx.x;
    if (i < 110592) {
        const int e = i & 7, l = (i >> 3) & 63, f = i >> 9;
        const int kk = f % 6, oct = f / 6;
        const int R = oct * 16 + (l & 15), C = kk * 32 + (l >> 4) * 8 + e;
        float v = qkv_w[R * 192 + C];
        if (oct < 12) v *= SCALE;
        W1f[i] = f2bf(v);
    }
    if (i < 36864) {
        const int e = i & 7, l = (i >> 3) & 63, f = i >> 9;
        const int c2t = f / 6, H = f % 6;
        const int R = c2t * 16 + (l & 15);
        const int C = H * 32 + (e >> 2) * 16 + (l >> 4) * 4 + (e & 3);
        W2p[i] = f2bf(proj_w[R * 192 + C]);
    }
    if (i < 576) qkvbs[i] = (i < 192) ? qkv_b[i] * SCALE : qkv_b[i];
    if (i < 6 * NTOK * 64) {                 // biasT[h][j][i], i padded to 64
        const int h = i / (NTOK * 64), j = (i / 64) % NTOK, ii = i % 64;
        biasT[i] = (ii < NTOK) ? rpb[rel[ii * NTOK + j] * 6 + h] : 0.f;
    }
}

extern "C" __global__ void __launch_bounds__(512, 1)
wattn_fused(const float* __restrict__ x,
            const float* __restrict__ mask,
            const float* __restrict__ proj_b,
            const unsigned short* __restrict__ W1f,
            const unsigned short* __restrict__ W2p,
            const float* __restrict__ qkvbs,
            const float* __restrict__ biasT,
            float* __restrict__ out)
{
    extern __shared__ char smem[];
    char* const OBX = smem;
    #define XB(w) (smem + (w) * 25600)
    #define KB(w) (smem + 51200 + (w) * 24576)
    #define VT(w) (smem + 100352 + (w) * 27648)

    const int tid  = threadIdx.x;
    const int wave = tid >> 6;
    const int lane = tid & 63;
    const int g    = lane >> 4;
    const int jn   = lane & 15;
    const int qt   = wave & 3;
    const int hh   = wave >> 2;
    const size_t b2 = (size_t)blockIdx.x * 2;

    // ---- prefetch mask (2 windows) into registers; stage x -> bf16 LDS ----
    float mreg[10];
    {
        const float* mb = mask + (b2 & (NWIN - 1)) * (NTOK * NTOK);
#pragma unroll
        for (int u = 0; u < 10; ++u) {
            const int i = tid + u * 512;
            mreg[u] = (i < 2 * NTOK * NTOK) ? mb[i] : 0.f;
        }
    }
#pragma unroll
    for (int u = 0; u < 6; ++u) {            // zero pad rows 49..63, both windows
        const int i = tid + u * 512;
        if (i < 3000) {
            const int w = i / 1500, e = i % 1500;
            *(unsigned int*)(XB(w) + (49 + e / 100) * 400 + (e % 100) * 4) = 0u;
        }
    }
    {
        const float4* xw = (const float4*)(x + b2 * 9408);
#pragma unroll
        for (int u = 0; u < 10; ++u) {
            const int i = tid + u * 512;
            if (i < 4704) {
                float4 v = xw[i];
                const int w = i / 2352, e = i % 2352;
                *(ull*)(XB(w) + (e / 48) * 400 + (e % 48) * 8) =
                    (ull)f2bf(v.x) | ((ull)f2bf(v.y) << 16) |
                    ((ull)f2bf(v.z) << 32) | ((ull)f2bf(v.w) << 48);
            }
        }
    }
    __syncthreads();                                              // B1

    // ---- Q: this wave's 6 channel-tiles x its token tile, both windows ----
    bfx8 xq[2][6];
#pragma unroll
    for (int w = 0; w < 2; ++w)
#pragma unroll
        for (int kk = 0; kk < 6; ++kk)
            xq[w][kk] = *(const bfx8*)(XB(w) + (qt * 16 + jn) * 400 + kk * 64 + g * 16);

    BF8 qf[2][3];
#pragma unroll
    for (int q = 0; q < 6; ++q) {
        const int oct = hh * 6 + q;
        bfx8 wq[6];
#pragma unroll
        for (int kk = 0; kk < 6; ++kk)
            wq[kk] = *(const bfx8*)(W1f + ((size_t)(oct * 6 + kk) * 64 + lane) * 8);
        const f32x4 binit = *(const f32x4*)(qkvbs + oct * 16 + 4 * g);
#pragma unroll
        for (int w = 0; w < 2; ++w) {
            f32x4 acc = binit;
#pragma unroll
            for (int kk = 0; kk < 6; ++kk)
                acc = __builtin_amdgcn_mfma_f32_16x16x32_bf16(wq[kk], xq[w][kk], acc, 0, 0, 0);
#pragma unroll
            for (int r = 0; r < 4; ++r)
                qf[w][q >> 1].u[(q & 1) * 4 + r] = f2bf(acc[r]);
        }
    }

    // ---- K (hh=0, swapped) / V (hh=1, unswapped): 3 ch-tiles x 4 tok-tiles x 2 w ----
    bfx8 af[3][6];
#pragma unroll
    for (int oo = 0; oo < 3; ++oo) {
        const int oct = (hh ? 24 : 12) + qt * 3 + oo;
#pragma unroll
        for (int kk = 0; kk < 6; ++kk)
            af[oo][kk] = *(const bfx8*)(W1f + ((size_t)(oct * 6 + kk) * 64 + lane) * 8);
    }
#pragma unroll
    for (int tt = 0; tt < 4; ++tt) {
        bfx8 xf[2][6];
#pragma unroll
        for (int w = 0; w < 2; ++w)
#pragma unroll
            for (int kk = 0; kk < 6; ++kk)
                xf[w][kk] = *(const bfx8*)(XB(w) + (tt * 16 + jn) * 400 + kk * 64 + g * 16);
#pragma unroll
        for (int oo = 0; oo < 3; ++oo) {
            const int ct12 = qt * 3 + oo;                         // 0..11
            if (!hh) {
                const f32x4 binit = *(const f32x4*)(qkvbs + (12 + ct12) * 16 + 4 * g);
#pragma unroll
                for (int w = 0; w < 2; ++w) {
                    f32x4 acc = binit;
#pragma unroll
                    for (int kk = 0; kk < 6; ++kk)
                        acc = __builtin_amdgcn_mfma_f32_16x16x32_bf16(af[oo][kk], xf[w][kk], acc, 0, 0, 0);
                    *(ull*)(KB(w) + ((tt * 6 + (ct12 >> 1)) * 64 + lane) * 16 + (ct12 & 1) * 8) = pack4(acc);
                }
            } else {
                const float bv = qkvbs[(24 + ct12) * 16 + jn];
                const f32x4 binit = {bv, bv, bv, bv};
#pragma unroll
                for (int w = 0; w < 2; ++w) {
                    f32x4 acc = binit;
#pragma unroll
                    for (int kk = 0; kk < 6; ++kk)
                        acc = __builtin_amdgcn_mfma_f32_16x16x32_bf16(xf[w][kk], af[oo][kk], acc, 0, 0, 0);
                    *(ull*)(VT(w) + (ct12 * 16 + jn) * 144 + (tt >> 1) * 64 + g * 16 + (tt & 1) * 8) = pack4(acc);
                }
            }
        }
    }
    __syncthreads();                                              // B2

    // ---- stage transposed mask into dead xb region ----
#pragma unroll
    for (int u = 0; u < 10; ++u) {
        const int i = tid + u * 512;
        if (i < 2 * NTOK * NTOK) {
            const int w = i / (NTOK * NTOK), e = i % (NTOK * NTOK);
            *(float*)(XB(w) + ((e % NTOK) * 65 + e / NTOK) * 4) = mreg[u];
        }
    }
    __syncthreads();                                              // B3

    // ---- attention: 3 heads x 2 windows per wave, barrier-free ----
    float mv[2][4][4];
#pragma unroll
    for (int w = 0; w < 2; ++w)
#pragma unroll
        for (int kt = 0; kt < 4; ++kt)
#pragma unroll
            for (int r = 0; r < 4; ++r) {
                const int j = kt * 16 + 4 * g + r;
                const int jc = j < NTOK ? j : NTOK - 1;
                mv[w][kt][r] = *(const float*)(XB(w) + (jc * 65 + qt * 16 + jn) * 4);
            }

    BF8 obf[2][3];
#pragma unroll
    for (int hl = 0; hl < 3; ++hl) {
        const int H = hh * 3 + hl;
        float bm[4][4];
#pragma unroll
        for (int kt = 0; kt < 4; ++kt)
#pragma unroll
            for (int r = 0; r < 4; ++r) {
                const int j = kt * 16 + 4 * g + r;
                const int jc = j < NTOK ? j : NTOK - 1;
                bm[kt][r] = biasT[((size_t)H * NTOK + jc) * 64 + qt * 16 + jn];
            }
#pragma unroll
        for (int w = 0; w < 2; ++w) {
            f32x4 s[4];
#pragma unroll
            for (int kt = 0; kt < 4; ++kt) {
                bfx8 kf = *(const bfx8*)(KB(w) + ((kt * 6 + H) * 64 + lane) * 16);
                f32x4 z = {0.f, 0.f, 0.f, 0.f};
                s[kt] = __builtin_amdgcn_mfma_f32_16x16x32_bf16(kf, qf[w][hl].v, z, 0, 0, 0);
            }
            float p[4][4], mx = -1e30f;
#pragma unroll
            for (int kt = 0; kt < 4; ++kt)
#pragma unroll
                for (int r = 0; r < 4; ++r) {
                    const int j = kt * 16 + 4 * g + r;
                    const float v = (j < NTOK) ? s[kt][r] + bm[kt][r] + mv[w][kt][r] : -1e30f;
                    p[kt][r] = v;
                    mx = fmaxf(mx, v);
                }
            mx = fmaxf(mx, __shfl_xor(mx, 16));
            mx = fmaxf(mx, __shfl_xor(mx, 32));
            float sum = 0.f;
#pragma unroll
            for (int kt = 0; kt < 4; ++kt)
#pragma unroll
                for (int r = 0; r < 4; ++r) {
                    p[kt][r] = __expf(p[kt][r] - mx);
                    sum += p[kt][r];
                }
            sum += __shfl_xor(sum, 16);
            sum += __shfl_xor(sum, 32);
            const float inv = 1.f / sum;
            BF8 p01, p23;
#pragma unroll
            for (int r = 0; r < 4; ++r) {
                p01.u[r] = f2bf(p[0][r]); p01.u[4 + r] = f2bf(p[1][r]);
                p23.u[r] = f2bf(p[2][r]); p23.u[4 + r] = f2bf(p[3][r]);
            }
#pragma unroll
            for (int ct = 0; ct < 2; ++ct) {
                const int row = H * 32 + ct * 16 + jn;
                bfx8 v0 = *(const bfx8*)(VT(w) + row * 144 + g * 16);
                bfx8 v1 = *(const bfx8*)(VT(w) + row * 144 + 64 + g * 16);
                f32x4 o = {0.f, 0.f, 0.f, 0.f};
                o = __builtin_amdgcn_mfma_f32_16x16x32_bf16(v0, p01.v, o, 0, 0, 0);
                o = __builtin_amdgcn_mfma_f32_16x16x32_bf16(v1, p23.v, o, 0, 0, 0);
#pragma unroll
                for (int r = 0; r < 4; ++r)
                    obf[w][hl].u[ct * 4 + r] = f2bf(o[r] * inv);
            }
        }
    }
    __syncthreads();                                              // B4

    // ---- exchange O frags across head-halves (bf16, frag-blocked) ----
#pragma unroll
    for (int w = 0; w < 2; ++w)
#pragma unroll
        for (int hl = 0; hl < 3; ++hl)
            *(bfx8*)(OBX + ((((w * 2 + hh) * 4 + qt) * 3 + hl) * 64 + lane) * 16) = obf[w][hl].v;
    __syncthreads();                                              // B5

    // ---- proj: wave handles 6 out-ch tiles (its half), full K=192, direct store ----
    const int oh = 1 - hh;
    float* outp = out + b2 * 9408;
#pragma unroll
    for (int c6 = 0; c6 < 6; ++c6) {
        const int c2t = hh * 6 + c6;
        bfx8 wf[6];
#pragma unroll
        for (int H = 0; H < 6; ++H)
            wf[H] = *(const bfx8*)(W2p + ((size_t)(c2t * 6 + H) * 64 + lane) * 8);
        const f32x4 pb = *(const f32x4*)(proj_b + c2t * 16 + 4 * g);
#pragma unroll
        for (int w = 0; w < 2; ++w) {
            f32x4 acc = pb;
#pragma unroll
            for (int hl = 0; hl < 3; ++hl) {
                acc = __builtin_amdgcn_mfma_f32_16x16x32_bf16(wf[hh * 3 + hl], obf[w][hl].v, acc, 0, 0, 0);
                bfx8 ob2 = *(const bfx8*)(OBX + ((((w * 2 + oh) * 4 + qt) * 3 + hl) * 64 + lane) * 16);
                acc = __builtin_amdgcn_mfma_f32_16x16x32_bf16(wf[oh * 3 + hl], ob2, acc, 0, 0, 0);
            }
            if (qt * 16 + jn < NTOK)
                *(f32x4*)(outp + (size_t)w * 9408 + (qt * 16 + jn) * 192 + c2t * 16 + 4 * g) = acc;
        }
    }
}

extern "C" void kernel_launch(void* const* d_in, const int* in_sizes, int n_in,
                              void* d_out, int out_size, void* d_ws, size_t ws_size,
                              hipStream_t stream) {
    const float* x      = (const float*)d_in[0];
    const float* mask   = (const float*)d_in[1];
    const float* qkv_w  = (const float*)d_in[2];
    const float* qkv_b  = (const float*)d_in[3];
    const float* proj_w = (const float*)d_in[4];
    const float* proj_b = (const float*)d_in[5];
    const float* rpb    = (const float*)d_in[6];
    const int*   rel    = (const int*)d_in[7];
    float* outp = (float*)d_out;

    char* ws = (char*)d_ws;
    unsigned short* W1f = (unsigned short*)ws;                     // 221184 B
    unsigned short* W2p = (unsigned short*)(ws + 221184);          //  73728 B
    float* qkvbs        = (float*)(ws + 221184 + 73728);           //   2304 B
    float* biasT        = (float*)(ws + 221184 + 73728 + 2304);    //  75264 B

    hipFuncSetAttribute((const void*)wattn_fused,
                        hipFuncAttributeMaxDynamicSharedMemorySize, SMEM_BYTES);

    wattn_prep<<<432, 256, 0, stream>>>(qkv_w, proj_w, rpb, rel, qkv_b,
                                        W1f, W2p, qkvbs, biasT);
    wattn_fused<<<4096, 512, SMEM_BYTES, stream>>>(x, mask, proj_b,
                                                   W1f, W2p, qkvbs, biasT, outp);
}